// Round 13
// baseline (382.230 us; speedup 1.0000x reference)
//
#include <hip/hip_runtime.h>
#include <hip/hip_bf16.h>

typedef unsigned short u16;
typedef short bf16x8 __attribute__((ext_vector_type(8)));
typedef float f32x4 __attribute__((ext_vector_type(4)));
typedef float f32x2 __attribute__((ext_vector_type(2)));

__device__ __forceinline__ u16 f2b(float f) {
    unsigned x = __float_as_uint(f);
    return (u16)((x + 0x7fffu + ((x >> 16) & 1u)) >> 16);
}

// pack two f32 to bf16x2 by truncation: one v_perm_b32
__device__ __forceinline__ int pkbf(float lo, float hi) {
    return __builtin_amdgcn_perm(__float_as_uint(hi), __float_as_uint(lo), 0x07060302);
}

// packed dual-f32 FMA: acc = f * ex + acc (VOP3P)
__device__ __forceinline__ void pkfma(f32x2& acc, f32x2 f, f32x2 ex) {
    asm("v_pk_fma_f32 %0, %1, %2, %0" : "+v"(acc) : "v"(f), "v"(ex));
}

// ---------------- W^T cast + workspace zeroing (absorbs 2 memset dispatches) --------------
__global__ __launch_bounds__(256) void cast_wt_kernel(const float* __restrict__ W,
                                                      u16* __restrict__ Wt,
                                                      int* __restrict__ deg,
                                                      float* __restrict__ partAB, int R2) {
    __shared__ u16 tile[64][65];
    int tx = threadIdx.x & 63, ty = threadIdx.x >> 6;  // 64 x 4
    int bx = blockIdx.x & 7, by = blockIdx.x >> 3;
    // grid-stride zeroing (64 blocks x 256 threads = 16384)
    int gid = blockIdx.x * 256 + threadIdx.x;
    for (int i = gid; i < R2; i += 16384) deg[i] = 0;
    for (int i = gid; i < 2 * 64 * 512; i += 16384) partAB[i] = 0.f;
#pragma unroll
    for (int r = 0; r < 16; ++r) {
        int row = ty + (r << 2);
        tile[tx][row] = f2b(W[(by * 64 + row) * 512 + bx * 64 + tx]);
    }
    __syncthreads();
#pragma unroll
    for (int r = 0; r < 16; ++r) {
        int row = ty + (r << 2);
        Wt[(bx * 64 + row) * 512 + by * 64 + tx] = tile[row][tx];
    }
}

// ---------------- GEMM fused v6: double-buffered k-loop + LDS-staged h8 epilogue ----------
__global__ __launch_bounds__(256, 2) void gemm_fused6(
    const float* __restrict__ xA, const float* __restrict__ xW, const u16* __restrict__ Bt,
    unsigned char* __restrict__ h8, const float* __restrict__ att_src,
    const float* __restrict__ att_dst, float* __restrict__ asrc, float* __restrict__ adst,
    int N, int Mpad) {
    __shared__ float lA[2][64 * 32];   // 16 KB
    __shared__ u16 lB[2][512 * 32];    // 64 KB
    const int tid = threadIdx.x;
    const int w = tid >> 6, l = tid & 63;   // wave w = head w
    const int row0 = blockIdx.x * 64;
    const int head = w;
    const int mlane = l & 15, quad = l >> 4;
    const int R2v = 2 * Mpad;

    const float* src = (row0 >= Mpad) ? xW : xA;
    const int rbase = row0 - (row0 >= Mpad ? Mpad : 0);
    const int arow = (l >> 3);                             // A row (mod 8) at stage time
    const int acol = (((l & 7) ^ arow) << 2);              // pre-swizzled source chunk (floats)
    const int brow = (l >> 2);                             // B row (mod 16) at stage time
    const int bcol = (((l & 3) ^ ((l >> 3) & 3)) << 3);    // pre-swizzled source chunk (u16)

    auto stage = [&](int b, int k0) {
#pragma unroll
        for (int g = 0; g < 2; ++g) {
            int lrow = rbase + (w << 4) + (g << 3) + arow;
            lrow = min(lrow, N - 1);  // pad rows: clamp (results are don't-care)
            const float* ga = src + (size_t)lrow * 512 + k0 + acol;
            float* la = &lA[b][((w << 4) + (g << 3)) << 5];  // wave-uniform base, linear dest
            __builtin_amdgcn_global_load_lds((const __attribute__((address_space(1))) void*)ga,
                                             (__attribute__((address_space(3))) void*)la, 16, 0, 0);
        }
#pragma unroll
        for (int s = 0; s < 8; ++s) {
            const u16* gb = Bt + (size_t)((w << 7) + (s << 4) + brow) * 512 + (k0 + bcol);
            u16* lb = &lB[b][((w << 7) + (s << 4)) << 5];  // wave-uniform base, linear dest
            __builtin_amdgcn_global_load_lds((const __attribute__((address_space(1))) void*)gb,
                                             (__attribute__((address_space(3))) void*)lb, 16, 0, 0);
        }
    };

    f32x4 acc[4][8];
#pragma unroll
    for (int i = 0; i < 4; i++)
#pragma unroll
        for (int j = 0; j < 8; j++) acc[i][j] = f32x4{0.f, 0.f, 0.f, 0.f};

    stage(0, 0);
    __syncthreads();
    int cur = 0;
    for (int t = 0; t < 16; ++t) {
        if (t < 15) stage(cur ^ 1, (t + 1) << 5);  // next-tile loads in flight under compute
        bf16x8 af[4], bfr[8];
#pragma unroll
        for (int i = 0; i < 4; i++) {
            const float* rb = &lA[cur][(i * 16 + mlane) * 32];
            float4 f0 = *(const float4*)(rb + (((quad * 2) ^ (mlane & 7)) << 2));
            float4 f1 = *(const float4*)(rb + (((quad * 2 + 1) ^ (mlane & 7)) << 2));
            int* ai = (int*)&af[i];
            ai[0] = pkbf(f0.x, f0.y);
            ai[1] = pkbf(f0.z, f0.w);
            ai[2] = pkbf(f1.x, f1.y);
            ai[3] = pkbf(f1.z, f1.w);
        }
#pragma unroll
        for (int j = 0; j < 8; j++)
            bfr[j] = *(const bf16x8*)&lB[cur][((w << 7) + j * 16 + mlane) * 32 +
                                             ((quad ^ ((mlane >> 1) & 3)) << 3)];
#pragma unroll
        for (int i = 0; i < 4; i++)
#pragma unroll
            for (int j = 0; j < 8; j++)
                acc[i][j] = __builtin_amdgcn_mfma_f32_16x16x32_bf16(af[i], bfr[j], acc[i][j], 0, 0, 0);
        __syncthreads();  // drains next-tile loads; also protects buffer reuse
        cur ^= 1;
    }

    float as_j[8], ad_j[8];
#pragma unroll
    for (int j = 0; j < 8; j++) {
        as_j[j] = att_src[(head << 7) + j * 16 + mlane];
        ad_j[j] = att_dst[(head << 7) + j * 16 + mlane];
    }
#pragma unroll
    for (int i = 0; i < 4; i++) {
#pragma unroll
        for (int r = 0; r < 4; r++) {
            float vs = 0.f, vd = 0.f;
#pragma unroll
            for (int j = 0; j < 8; j++) {
                float hv = acc[i][j][r];
                vs += hv * as_j[j];
                vd += hv * ad_j[j];
            }
#pragma unroll
            for (int o = 8; o >= 1; o >>= 1) {
                vs += __shfl_xor(vs, o);
                vd += __shfl_xor(vd, o);
            }
            if (mlane == 0) {
                int rg = row0 + i * 16 + quad * 4 + r;
                asrc[head * R2v + rg] = vs;
                adst[head * R2v + rg] = vd;
            }
        }
    }

    // h8 epilogue: fp8-pack into LDS tile (64 rows x 512 bytes, XOR-swizzled), then
    // coalesced dwordx4 stores. lB[0] is free after the final k-loop barrier.
    unsigned char* hstage = (unsigned char*)&lB[0][0];  // 32 KB
#pragma unroll
    for (int i = 0; i < 4; i++)
#pragma unroll
        for (int j = 0; j < 8; j++)
#pragma unroll
            for (int r = 0; r < 4; r++) {
                int row = i * 16 + quad * 4 + r;
                int colb = (w << 7) + j * 16 + mlane;  // [head*128 + cc]
                float v = acc[i][j][r];
                unsigned pk = __builtin_amdgcn_cvt_pk_fp8_f32(v, v, 0, false);
                hstage[row * 512 + (colb ^ ((row & 7) << 4))] = (unsigned char)(pk & 0xff);
            }
    __syncthreads();
#pragma unroll
    for (int k = 0; k < 8; ++k) {
        int c = (k << 8) + tid;   // chunk index [0,2048): 2048 x 16B = 32 KB
        int hd = c >> 9;          // 512 chunks per head
        int rem = c & 511;
        int row = rem >> 3;       // 8 chunks per 128-byte head-row
        int cch = rem & 7;
        int lofs = row * 512 + ((((hd << 7) + (cch << 4))) ^ ((row & 7) << 4));
        int4 v = *(const int4*)&hstage[lofs];
        *(int4*)&h8[(((size_t)(hd * R2v + row0 + row)) << 7) + (cch << 4)] = v;
    }
}

// ---------------- CSR over hrow space [0, 2*Mpad) ----------------
__global__ void csr_count(const int* __restrict__ adj, const int* __restrict__ wadj,
                          int E, int Mpad, int* __restrict__ deg) {
    int i = blockIdx.x * blockDim.x + threadIdx.x;
    if (i < 2 * E) {
        int d = (i < E) ? adj[E + i] : (wadj[E + (i - E)] + Mpad);
        atomicAdd(&deg[d], 1);
    }
}

// ---------------- single-block full scan: deg -> off/cursor/self-loop csrc ----------------
// Whole deg array (R2=40192 ints = 157 KB) fits in one CU's LDS. Replaces scanA+scanB+scanC
// (3 dispatches -> 1). 1024 threads: coalesced load (+self-loop), per-thread 40-chunk sum,
// wave/block scan of partials, in-LDS conversion to exclusive prefixes, coalesced writes.
__global__ __launch_bounds__(1024) void scan_fused(
    const int* __restrict__ deg, int* __restrict__ off, int* __restrict__ cursor,
    int* __restrict__ csrc, int n, int N, int Mpad) {
    __shared__ int s[40192];
    __shared__ int wsum[16];
    __shared__ int stotal;
    const int t = threadIdx.x;
    const int lane = t & 63, wid = t >> 6;
    // coalesced load, + self-loop for valid rows
    for (int i = t; i < n; i += 1024) {
        int valid = (i < N) || (i >= Mpad && i < Mpad + N);
        s[i] = deg[i] + valid;
    }
    __syncthreads();
    // per-thread chunk sum (chunk = 40 contiguous)
    const int base = t * 40;
    int sum = 0;
#pragma unroll 4
    for (int j = 0; j < 40; ++j) {
        int i = base + j;
        if (i < n) sum += s[i];
    }
    // wave inclusive scan
    int x = sum;
#pragma unroll
    for (int o = 1; o < 64; o <<= 1) {
        int y = __shfl_up(x, (unsigned)o, 64);
        if (lane >= o) x += y;
    }
    if (lane == 63) wsum[wid] = x;
    __syncthreads();
    int woff = 0;
    for (int j = 0; j < wid; ++j) woff += wsum[j];
    int excl = woff + x - sum;  // exclusive prefix of this thread's chunk
    if (t == 1023) stotal = excl + sum;
    // convert chunk in LDS to exclusive prefixes
    int run = excl;
#pragma unroll 4
    for (int j = 0; j < 40; ++j) {
        int i = base + j;
        if (i < n) {
            int d = s[i];
            s[i] = run;
            run += d;
        }
    }
    __syncthreads();
    // coalesced writes
    for (int i = t; i < n; i += 1024) {
        int o = s[i];
        int valid = (i < N) || (i >= Mpad && i < Mpad + N);
        off[i] = o;
        cursor[i] = o + valid;
        if (valid) csrc[o] = i;  // self loop at segment start
    }
    if (t == 0) off[n] = stotal;
}

__global__ void csr_scatter(const int* __restrict__ adj, const int* __restrict__ wadj,
                            int E, int Mpad, int* __restrict__ cursor, int* __restrict__ csrc) {
    int i = blockIdx.x * blockDim.x + threadIdx.x;
    if (i < 2 * E) {
        int s, d;
        if (i < E) {
            s = adj[i];
            d = adj[E + i];
        } else {
            s = wadj[i - E] + Mpad;
            d = wadj[E + (i - E)] + Mpad;
        }
        int p = atomicAdd(&cursor[d], 1);
        csrc[p] = s;
    }
}

// ---------------- fused softmax + gather v14: (head,graph)-per-XCD, 8 blocks/CU -----------
// Same body as v13 (78.6 us, VGPR 40). launch_bounds(256,8) fits the 40-reg live set in the
// 64-reg cap (v10's spill was an ~80-reg live set) -> 2048 blocks = 256 CU x 8 co-resident,
// single round, more TLP against the residual gather latency.
__global__ __launch_bounds__(256, 8) void gat_aggregate14(
    const unsigned char* __restrict__ h8, const float* __restrict__ asrc,
    const float* __restrict__ adst, const int* __restrict__ off, const int* __restrict__ csrc,
    const float* __restrict__ bias, float* __restrict__ partAB, int Mpad) {
    const int R2 = 2 * Mpad;
    __shared__ float spool[128];  // this block's (head, graph) 128 channels
    int tid = threadIdx.x;
    if (tid < 128) spool[tid] = 0.f;
    __syncthreads();
    const int wv = tid >> 6, l = tid & 63;
    const int gi = (l >> 3) & 3;  // edge slot within half (0..3)
    const int hi = l >> 5;        // which dst of the pair (0/1)
    const int chb = (l & 7) << 4; // channel byte offset within 128 (16 B per lane)
    const int head = (blockIdx.x & 7) >> 1;
    const int gc = blockIdx.x & 1;  // graph 0=A, 1=B
    const unsigned char* h8h = h8 + (((size_t)head * R2) << 7);
    const float* ash = asrc + (size_t)head * R2;
    const float* adh = adst + (size_t)head * R2;
    float bb[16];
#pragma unroll
    for (int k = 0; k < 16; ++k) bb[k] = bias[head * 128 + chb + k];
    float pool[16];
#pragma unroll
    for (int k = 0; k < 16; ++k) pool[k] = 0.f;

    const int hb = gc * Mpad;
    const int half = Mpad >> 1;  // Mpad even; N even -> pairs never split valid/pad
    int widx = ((blockIdx.x >> 3) << 2) + wv;
    const int cstride = gridDim.x >> 1;  // (gridDim/8)*4

    for (int p = widx; p < half; p += cstride) {
        int d0 = (p << 1) + hb;
        int q0 = off[d0], q1 = off[d0 + 1], q2 = off[d0 + 2];
        int n0 = q1 - q0, n1 = q2 - q1;
        int nmax = max(n0, n1);
        if (nmax == 0) continue;  // pad pair
        int nm = hi ? n1 : n0;
        int qm = hi ? q1 : q0;
        float ad = adh[d0 + hi];
        f32x2 acc2[8];
#pragma unroll
        for (int j = 0; j < 8; ++j) acc2[j] = f32x2{0.f, 0.f};
        float dsum = 0.f;

        int i0 = gi, i1 = 4 + gi, i2 = 8 + gi, i3 = 12 + gi;
        int E0 = csrc[qm + ((i0 < nm) ? i0 : 0)];
        int E1 = csrc[qm + ((i1 < nm) ? i1 : 0)];
        int E2 = csrc[qm + ((i2 < nm) ? i2 : 0)];
        int E3 = csrc[qm + ((i3 < nm) ? i3 : 0)];
        float A0 = ash[E0];
        int4 H0 = *(const int4*)(h8h + (((size_t)E0) << 7) + chb);
        float A1 = ash[E1];
        int4 H1 = *(const int4*)(h8h + (((size_t)E1) << 7) + chb);

#pragma unroll 2
        for (int base = 0; base < nmax; base += 4) {
            int i4 = base + 16 + gi;
            int E4 = csrc[qm + ((i4 < nm) ? i4 : 0)];
            float A2 = ash[E2];
            int4 H2 = *(const int4*)(h8h + (((size_t)E2) << 7) + chb);
            float e = A0 + ad;
            float em = fmaxf(e, 0.2f * e);
            float ex = __expf(em);
            ex = ((base + gi) < nm) ? ex : 0.f;
            dsum += ex;
            f32x2 exv = {ex, ex};
            f32x2 f;
            f = __builtin_amdgcn_cvt_pk_f32_fp8(H0.x, false); pkfma(acc2[0], f, exv);
            f = __builtin_amdgcn_cvt_pk_f32_fp8(H0.x, true);  pkfma(acc2[1], f, exv);
            f = __builtin_amdgcn_cvt_pk_f32_fp8(H0.y, false); pkfma(acc2[2], f, exv);
            f = __builtin_amdgcn_cvt_pk_f32_fp8(H0.y, true);  pkfma(acc2[3], f, exv);
            f = __builtin_amdgcn_cvt_pk_f32_fp8(H0.z, false); pkfma(acc2[4], f, exv);
            f = __builtin_amdgcn_cvt_pk_f32_fp8(H0.z, true);  pkfma(acc2[5], f, exv);
            f = __builtin_amdgcn_cvt_pk_f32_fp8(H0.w, false); pkfma(acc2[6], f, exv);
            f = __builtin_amdgcn_cvt_pk_f32_fp8(H0.w, true);  pkfma(acc2[7], f, exv);
            A0 = A1; H0 = H1;
            A1 = A2; H1 = H2;
            E2 = E3; E3 = E4;
        }
        dsum += __shfl_xor(dsum, 8);
        dsum += __shfl_xor(dsum, 16);
#pragma unroll
        for (int j = 0; j < 8; ++j) {
            acc2[j].x += __shfl_xor(acc2[j].x, 8);
            acc2[j].y += __shfl_xor(acc2[j].y, 8);
            acc2[j].x += __shfl_xor(acc2[j].x, 16);
            acc2[j].y += __shfl_xor(acc2[j].y, 16);
        }
        if (nm > 0) {
            float inv = 1.f / (dsum + 1e-16f);
#pragma unroll
            for (int j = 0; j < 8; ++j) {
                float o0 = acc2[j].x * inv + bb[2 * j];
                float o1 = acc2[j].y * inv + bb[2 * j + 1];
                pool[2 * j] += fmaxf(o0, 0.01f * o0);
                pool[2 * j + 1] += fmaxf(o1, 0.01f * o1);
            }
        }
    }
    if ((l & 31) < 8) {
#pragma unroll
        for (int k = 0; k < 16; ++k) atomicAdd(&spool[chb + k], pool[k]);
    }
    __syncthreads();
    if (tid < 128) {
        int slot = (blockIdx.x >> 3) & 63;
        float* dp = partAB + (gc ? 64 * 512 : 0) + (slot << 9) + head * 128 + tid;
        atomicAdd(dp, spool[tid]);
    }
}

// ---------------- fused mean-pool reduce + fc + concat ----------------
__global__ __launch_bounds__(256) void fc_final2(
    const float* __restrict__ partAB, const float* __restrict__ w, const float* __restrict__ b,
    float* __restrict__ out, float invN) {
    __shared__ float gA[512], gB[512];
    __shared__ float rA[256], rB[256];
    int t = threadIdx.x;
    for (int i = t; i < 512; i += 256) {
        float sA = 0.f, sB = 0.f;
        for (int r = 0; r < 64; ++r) {
            sA += partAB[r * 512 + i];
            sB += partAB[64 * 512 + r * 512 + i];
        }
        gA[i] = sA * invN;
        gB[i] = sB * invN;
    }
    __syncthreads();
    int jj = t & 31, ks = t >> 5;
    int j = blockIdx.x * 32 + jj;
    float sA = 0.f, sB = 0.f;
    for (int k = ks * 64; k < ks * 64 + 64; ++k) {
        float wv = w[k * 512 + j];
        sA += gA[k] * wv;
        sB += gB[k] * wv;
    }
    rA[t] = sA;
    rB[t] = sB;
    __syncthreads();
    if (ks == 0) {
#pragma unroll
        for (int s2 = 1; s2 < 8; ++s2) {
            sA += rA[jj + 32 * s2];
            sB += rB[jj + 32 * s2];
        }
        sA += b[j];
        sB += b[j];
        sA = sA >= 0.f ? sA : 0.01f * sA;
        sB = sB >= 0.f ? sB : 0.01f * sB;
        out[j] = sA;
        out[512 + j] = sB;
        out[1024 + j] = sA - sB;
    }
}

// ---------------- launch ----------------
extern "C" void kernel_launch(void* const* d_in, const int* in_sizes, int n_in,
                              void* d_out, int out_size, void* d_ws, size_t ws_size,
                              hipStream_t stream) {
    const float* x = (const float*)d_in[0];
    const int* adj = (const int*)d_in[1];
    const float* wtx = (const float*)d_in[2];
    const int* wadj = (const int*)d_in[3];
    const float* W = (const float*)d_in[4];
    const float* att_s = (const float*)d_in[5];
    const float* att_d = (const float*)d_in[6];
    const float* bias = (const float*)d_in[7];
    const float* fc1w = (const float*)d_in[8];
    const float* fc1b = (const float*)d_in[9];
    float* out = (float*)d_out;

    const int N = in_sizes[0] / 512;  // 20000
    const int E = in_sizes[1] / 2;    // 320000
    const int Mpad = ((N + 127) / 128) * 128;
    const int R2 = 2 * Mpad;          // hrow space

    char* p = (char*)d_ws;
    auto alloc = [&](size_t bytes) -> char* {
        char* r = p;
        p += (bytes + 255) & ~(size_t)255;
        return r;
    };
    unsigned char* h8 = (unsigned char*)alloc((size_t)R2 * 512);
    u16* Wt = (u16*)alloc(512 * 512 * 2);
    float* asrc = (float*)alloc((size_t)R2 * 4 * 4);
    float* adst = (float*)alloc((size_t)R2 * 4 * 4);
    int* deg = (int*)alloc((size_t)R2 * 4);
    int* off = (int*)alloc((size_t)(R2 + 1) * 4);
    int* cursor = (int*)alloc((size_t)R2 * 4);
    int* csrc = (int*)alloc((size_t)2 * (E + N) * 4);
    float* partAB = (float*)alloc((size_t)2 * 64 * 512 * 4);

    // cast_wt also zeroes deg + partAB (absorbs the 2 memset dispatches)
    cast_wt_kernel<<<64, 256, 0, stream>>>(W, Wt, deg, partAB, R2);

    // CSR build (independent of GEMM)
    csr_count<<<(2 * E + 255) / 256, 256, 0, stream>>>(adj, wadj, E, Mpad, deg);
    scan_fused<<<1, 1024, 0, stream>>>(deg, off, cursor, csrc, R2, N, Mpad);
    csr_scatter<<<(2 * E + 255) / 256, 256, 0, stream>>>(adj, wadj, E, Mpad, cursor, csrc);

    // fused GEMM: one block per 64-row tile, all heads (A staged once, dbuf + swizzled LDS)
    gemm_fused6<<<R2 / 64, 256, 0, stream>>>(x, wtx, Wt, h8, att_s, att_d, asrc, adst, N, Mpad);

    gat_aggregate14<<<2048, 256, 0, stream>>>(h8, asrc, adst, off, csrc, bias, partAB, Mpad);

    fc_final2<<<16, 256, 0, stream>>>(partAB, fc1w, fc1b, out, 1.0f / (float)N);
}

// Round 14
// 356.348 us; speedup vs baseline: 1.0726x; 1.0726x over previous
//
#include <hip/hip_runtime.h>
#include <hip/hip_bf16.h>

typedef unsigned short u16;
typedef short bf16x8 __attribute__((ext_vector_type(8)));
typedef float f32x4 __attribute__((ext_vector_type(4)));
typedef float f32x2 __attribute__((ext_vector_type(2)));

__device__ __forceinline__ u16 f2b(float f) {
    unsigned x = __float_as_uint(f);
    return (u16)((x + 0x7fffu + ((x >> 16) & 1u)) >> 16);
}

// pack two f32 to bf16x2 by truncation: one v_perm_b32
__device__ __forceinline__ int pkbf(float lo, float hi) {
    return __builtin_amdgcn_perm(__float_as_uint(hi), __float_as_uint(lo), 0x07060302);
}

// packed dual-f32 FMA: acc = f * ex + acc (VOP3P)
__device__ __forceinline__ void pkfma(f32x2& acc, f32x2 f, f32x2 ex) {
    asm("v_pk_fma_f32 %0, %1, %2, %0" : "+v"(acc) : "v"(f), "v"(ex));
}

// ---------------- W^T cast + workspace zeroing (absorbs 2 memset dispatches) --------------
__global__ __launch_bounds__(256) void cast_wt_kernel(const float* __restrict__ W,
                                                      u16* __restrict__ Wt,
                                                      int* __restrict__ deg,
                                                      float* __restrict__ partAB, int R2) {
    __shared__ u16 tile[64][65];
    int tx = threadIdx.x & 63, ty = threadIdx.x >> 6;  // 64 x 4
    int bx = blockIdx.x & 7, by = blockIdx.x >> 3;
    // grid-stride zeroing (64 blocks x 256 threads = 16384)
    int gid = blockIdx.x * 256 + threadIdx.x;
    for (int i = gid; i < R2; i += 16384) deg[i] = 0;
    for (int i = gid; i < 2 * 64 * 512; i += 16384) partAB[i] = 0.f;
#pragma unroll
    for (int r = 0; r < 16; ++r) {
        int row = ty + (r << 2);
        tile[tx][row] = f2b(W[(by * 64 + row) * 512 + bx * 64 + tx]);
    }
    __syncthreads();
#pragma unroll
    for (int r = 0; r < 16; ++r) {
        int row = ty + (r << 2);
        Wt[(bx * 64 + row) * 512 + by * 64 + tx] = tile[row][tx];
    }
}

// ---------------- GEMM fused v6: double-buffered k-loop + LDS-staged h8 epilogue ----------
__global__ __launch_bounds__(256, 2) void gemm_fused6(
    const float* __restrict__ xA, const float* __restrict__ xW, const u16* __restrict__ Bt,
    unsigned char* __restrict__ h8, const float* __restrict__ att_src,
    const float* __restrict__ att_dst, float* __restrict__ asrc, float* __restrict__ adst,
    int N, int Mpad) {
    __shared__ float lA[2][64 * 32];   // 16 KB
    __shared__ u16 lB[2][512 * 32];    // 64 KB
    const int tid = threadIdx.x;
    const int w = tid >> 6, l = tid & 63;   // wave w = head w
    const int row0 = blockIdx.x * 64;
    const int head = w;
    const int mlane = l & 15, quad = l >> 4;
    const int R2v = 2 * Mpad;

    const float* src = (row0 >= Mpad) ? xW : xA;
    const int rbase = row0 - (row0 >= Mpad ? Mpad : 0);
    const int arow = (l >> 3);                             // A row (mod 8) at stage time
    const int acol = (((l & 7) ^ arow) << 2);              // pre-swizzled source chunk (floats)
    const int brow = (l >> 2);                             // B row (mod 16) at stage time
    const int bcol = (((l & 3) ^ ((l >> 3) & 3)) << 3);    // pre-swizzled source chunk (u16)

    auto stage = [&](int b, int k0) {
#pragma unroll
        for (int g = 0; g < 2; ++g) {
            int lrow = rbase + (w << 4) + (g << 3) + arow;
            lrow = min(lrow, N - 1);  // pad rows: clamp (results are don't-care)
            const float* ga = src + (size_t)lrow * 512 + k0 + acol;
            float* la = &lA[b][((w << 4) + (g << 3)) << 5];  // wave-uniform base, linear dest
            __builtin_amdgcn_global_load_lds((const __attribute__((address_space(1))) void*)ga,
                                             (__attribute__((address_space(3))) void*)la, 16, 0, 0);
        }
#pragma unroll
        for (int s = 0; s < 8; ++s) {
            const u16* gb = Bt + (size_t)((w << 7) + (s << 4) + brow) * 512 + (k0 + bcol);
            u16* lb = &lB[b][((w << 7) + (s << 4)) << 5];  // wave-uniform base, linear dest
            __builtin_amdgcn_global_load_lds((const __attribute__((address_space(1))) void*)gb,
                                             (__attribute__((address_space(3))) void*)lb, 16, 0, 0);
        }
    };

    f32x4 acc[4][8];
#pragma unroll
    for (int i = 0; i < 4; i++)
#pragma unroll
        for (int j = 0; j < 8; j++) acc[i][j] = f32x4{0.f, 0.f, 0.f, 0.f};

    stage(0, 0);
    __syncthreads();
    int cur = 0;
    for (int t = 0; t < 16; ++t) {
        if (t < 15) stage(cur ^ 1, (t + 1) << 5);  // next-tile loads in flight under compute
        bf16x8 af[4], bfr[8];
#pragma unroll
        for (int i = 0; i < 4; i++) {
            const float* rb = &lA[cur][(i * 16 + mlane) * 32];
            float4 f0 = *(const float4*)(rb + (((quad * 2) ^ (mlane & 7)) << 2));
            float4 f1 = *(const float4*)(rb + (((quad * 2 + 1) ^ (mlane & 7)) << 2));
            int* ai = (int*)&af[i];
            ai[0] = pkbf(f0.x, f0.y);
            ai[1] = pkbf(f0.z, f0.w);
            ai[2] = pkbf(f1.x, f1.y);
            ai[3] = pkbf(f1.z, f1.w);
        }
#pragma unroll
        for (int j = 0; j < 8; j++)
            bfr[j] = *(const bf16x8*)&lB[cur][((w << 7) + j * 16 + mlane) * 32 +
                                             ((quad ^ ((mlane >> 1) & 3)) << 3)];
#pragma unroll
        for (int i = 0; i < 4; i++)
#pragma unroll
            for (int j = 0; j < 8; j++)
                acc[i][j] = __builtin_amdgcn_mfma_f32_16x16x32_bf16(af[i], bfr[j], acc[i][j], 0, 0, 0);
        __syncthreads();  // drains next-tile loads; also protects buffer reuse
        cur ^= 1;
    }

    float as_j[8], ad_j[8];
#pragma unroll
    for (int j = 0; j < 8; j++) {
        as_j[j] = att_src[(head << 7) + j * 16 + mlane];
        ad_j[j] = att_dst[(head << 7) + j * 16 + mlane];
    }
#pragma unroll
    for (int i = 0; i < 4; i++) {
#pragma unroll
        for (int r = 0; r < 4; r++) {
            float vs = 0.f, vd = 0.f;
#pragma unroll
            for (int j = 0; j < 8; j++) {
                float hv = acc[i][j][r];
                vs += hv * as_j[j];
                vd += hv * ad_j[j];
            }
#pragma unroll
            for (int o = 8; o >= 1; o >>= 1) {
                vs += __shfl_xor(vs, o);
                vd += __shfl_xor(vd, o);
            }
            if (mlane == 0) {
                int rg = row0 + i * 16 + quad * 4 + r;
                asrc[head * R2v + rg] = vs;
                adst[head * R2v + rg] = vd;
            }
        }
    }

    // h8 epilogue: fp8-pack into LDS tile (64 rows x 512 bytes, XOR-swizzled), then
    // coalesced dwordx4 stores. lB[0] is free after the final k-loop barrier.
    unsigned char* hstage = (unsigned char*)&lB[0][0];  // 32 KB
#pragma unroll
    for (int i = 0; i < 4; i++)
#pragma unroll
        for (int j = 0; j < 8; j++)
#pragma unroll
            for (int r = 0; r < 4; r++) {
                int row = i * 16 + quad * 4 + r;
                int colb = (w << 7) + j * 16 + mlane;  // [head*128 + cc]
                float v = acc[i][j][r];
                unsigned pk = __builtin_amdgcn_cvt_pk_fp8_f32(v, v, 0, false);
                hstage[row * 512 + (colb ^ ((row & 7) << 4))] = (unsigned char)(pk & 0xff);
            }
    __syncthreads();
#pragma unroll
    for (int k = 0; k < 8; ++k) {
        int c = (k << 8) + tid;   // chunk index [0,2048): 2048 x 16B = 32 KB
        int hd = c >> 9;          // 512 chunks per head
        int rem = c & 511;
        int row = rem >> 3;       // 8 chunks per 128-byte head-row
        int cch = rem & 7;
        int lofs = row * 512 + ((((hd << 7) + (cch << 4))) ^ ((row & 7) << 4));
        int4 v = *(const int4*)&hstage[lofs];
        *(int4*)&h8[(((size_t)(hd * R2v + row0 + row)) << 7) + (cch << 4)] = v;
    }
}

// ---------------- CSR over hrow space [0, 2*Mpad) ----------------
__global__ void csr_count(const int* __restrict__ adj, const int* __restrict__ wadj,
                          int E, int Mpad, int* __restrict__ deg) {
    int i = blockIdx.x * blockDim.x + threadIdx.x;
    if (i < 2 * E) {
        int d = (i < E) ? adj[E + i] : (wadj[E + (i - E)] + Mpad);
        atomicAdd(&deg[d], 1);
    }
}

// ---------------- single-block full scan: deg -> off/cursor/self-loop csrc ----------------
__global__ __launch_bounds__(1024) void scan_fused(
    const int* __restrict__ deg, int* __restrict__ off, int* __restrict__ cursor,
    int* __restrict__ csrc, int n, int N, int Mpad) {
    __shared__ int s[40192];
    __shared__ int wsum[16];
    __shared__ int stotal;
    const int t = threadIdx.x;
    const int lane = t & 63, wid = t >> 6;
    for (int i = t; i < n; i += 1024) {
        int valid = (i < N) || (i >= Mpad && i < Mpad + N);
        s[i] = deg[i] + valid;
    }
    __syncthreads();
    const int base = t * 40;
    int sum = 0;
#pragma unroll 4
    for (int j = 0; j < 40; ++j) {
        int i = base + j;
        if (i < n) sum += s[i];
    }
    int x = sum;
#pragma unroll
    for (int o = 1; o < 64; o <<= 1) {
        int y = __shfl_up(x, (unsigned)o, 64);
        if (lane >= o) x += y;
    }
    if (lane == 63) wsum[wid] = x;
    __syncthreads();
    int woff = 0;
    for (int j = 0; j < wid; ++j) woff += wsum[j];
    int excl = woff + x - sum;  // exclusive prefix of this thread's chunk
    if (t == 1023) stotal = excl + sum;
    int run = excl;
#pragma unroll 4
    for (int j = 0; j < 40; ++j) {
        int i = base + j;
        if (i < n) {
            int d = s[i];
            s[i] = run;
            run += d;
        }
    }
    __syncthreads();
    for (int i = t; i < n; i += 1024) {
        int o = s[i];
        int valid = (i < N) || (i >= Mpad && i < Mpad + N);
        off[i] = o;
        cursor[i] = o + valid;
        if (valid) csrc[o] = i;  // self loop at segment start
    }
    if (t == 0) off[n] = stotal;
}

__global__ void csr_scatter(const int* __restrict__ adj, const int* __restrict__ wadj,
                            int E, int Mpad, int* __restrict__ cursor, int* __restrict__ csrc) {
    int i = blockIdx.x * blockDim.x + threadIdx.x;
    if (i < 2 * E) {
        int s, d;
        if (i < E) {
            s = adj[i];
            d = adj[E + i];
        } else {
            s = wadj[i - E] + Mpad;
            d = wadj[E + (i - E)] + Mpad;
        }
        int p = atomicAdd(&cursor[d], 1);
        csrc[p] = s;
    }
}

// ---------------- fused softmax + gather v13: (head,graph)-per-XCD, 3-deep pipeline --------
// REVERTED to the proven 78.6us config. launch_bounds(256,6) = 85-reg cap >= ~80-reg live
// set (acc2[16]+3x int4 pipeline+pool[16]+bb[16]). (256,8)'s 64-reg cap spilled (225 MB
// scratch writes, r13). OCCUPANCY KNOB EXHAUSTED for this kernel — never cap below 85.
__global__ __launch_bounds__(256, 6) void gat_aggregate13(
    const unsigned char* __restrict__ h8, const float* __restrict__ asrc,
    const float* __restrict__ adst, const int* __restrict__ off, const int* __restrict__ csrc,
    const float* __restrict__ bias, float* __restrict__ partAB, int Mpad) {
    const int R2 = 2 * Mpad;
    __shared__ float spool[128];  // this block's (head, graph) 128 channels
    int tid = threadIdx.x;
    if (tid < 128) spool[tid] = 0.f;
    __syncthreads();
    const int wv = tid >> 6, l = tid & 63;
    const int gi = (l >> 3) & 3;  // edge slot within half (0..3)
    const int hi = l >> 5;        // which dst of the pair (0/1)
    const int chb = (l & 7) << 4; // channel byte offset within 128 (16 B per lane)
    const int head = (blockIdx.x & 7) >> 1;
    const int gc = blockIdx.x & 1;  // graph 0=A, 1=B
    const unsigned char* h8h = h8 + (((size_t)head * R2) << 7);
    const float* ash = asrc + (size_t)head * R2;
    const float* adh = adst + (size_t)head * R2;
    float bb[16];
#pragma unroll
    for (int k = 0; k < 16; ++k) bb[k] = bias[head * 128 + chb + k];
    float pool[16];
#pragma unroll
    for (int k = 0; k < 16; ++k) pool[k] = 0.f;

    const int hb = gc * Mpad;
    const int half = Mpad >> 1;  // Mpad even; N even -> pairs never split valid/pad
    int widx = ((blockIdx.x >> 3) << 2) + wv;
    const int cstride = gridDim.x >> 1;  // (gridDim/8)*4

    for (int p = widx; p < half; p += cstride) {
        int d0 = (p << 1) + hb;
        int q0 = off[d0], q1 = off[d0 + 1], q2 = off[d0 + 2];
        int n0 = q1 - q0, n1 = q2 - q1;
        int nmax = max(n0, n1);
        if (nmax == 0) continue;  // pad pair
        int nm = hi ? n1 : n0;
        int qm = hi ? q1 : q0;
        float ad = adh[d0 + hi];
        f32x2 acc2[8];
#pragma unroll
        for (int j = 0; j < 8; ++j) acc2[j] = f32x2{0.f, 0.f};
        float dsum = 0.f;

        int i0 = gi, i1 = 4 + gi, i2 = 8 + gi, i3 = 12 + gi;
        int E0 = csrc[qm + ((i0 < nm) ? i0 : 0)];
        int E1 = csrc[qm + ((i1 < nm) ? i1 : 0)];
        int E2 = csrc[qm + ((i2 < nm) ? i2 : 0)];
        int E3 = csrc[qm + ((i3 < nm) ? i3 : 0)];
        float A0 = ash[E0];
        int4 H0 = *(const int4*)(h8h + (((size_t)E0) << 7) + chb);
        float A1 = ash[E1];
        int4 H1 = *(const int4*)(h8h + (((size_t)E1) << 7) + chb);

#pragma unroll 2
        for (int base = 0; base < nmax; base += 4) {
            int i4 = base + 16 + gi;
            int E4 = csrc[qm + ((i4 < nm) ? i4 : 0)];
            float A2 = ash[E2];
            int4 H2 = *(const int4*)(h8h + (((size_t)E2) << 7) + chb);
            float e = A0 + ad;
            float em = fmaxf(e, 0.2f * e);
            float ex = __expf(em);
            ex = ((base + gi) < nm) ? ex : 0.f;
            dsum += ex;
            f32x2 exv = {ex, ex};
            f32x2 f;
            f = __builtin_amdgcn_cvt_pk_f32_fp8(H0.x, false); pkfma(acc2[0], f, exv);
            f = __builtin_amdgcn_cvt_pk_f32_fp8(H0.x, true);  pkfma(acc2[1], f, exv);
            f = __builtin_amdgcn_cvt_pk_f32_fp8(H0.y, false); pkfma(acc2[2], f, exv);
            f = __builtin_amdgcn_cvt_pk_f32_fp8(H0.y, true);  pkfma(acc2[3], f, exv);
            f = __builtin_amdgcn_cvt_pk_f32_fp8(H0.z, false); pkfma(acc2[4], f, exv);
            f = __builtin_amdgcn_cvt_pk_f32_fp8(H0.z, true);  pkfma(acc2[5], f, exv);
            f = __builtin_amdgcn_cvt_pk_f32_fp8(H0.w, false); pkfma(acc2[6], f, exv);
            f = __builtin_amdgcn_cvt_pk_f32_fp8(H0.w, true);  pkfma(acc2[7], f, exv);
            A0 = A1; H0 = H1;
            A1 = A2; H1 = H2;
            E2 = E3; E3 = E4;
        }
        dsum += __shfl_xor(dsum, 8);
        dsum += __shfl_xor(dsum, 16);
#pragma unroll
        for (int j = 0; j < 8; ++j) {
            acc2[j].x += __shfl_xor(acc2[j].x, 8);
            acc2[j].y += __shfl_xor(acc2[j].y, 8);
            acc2[j].x += __shfl_xor(acc2[j].x, 16);
            acc2[j].y += __shfl_xor(acc2[j].y, 16);
        }
        if (nm > 0) {
            float inv = 1.f / (dsum + 1e-16f);
#pragma unroll
            for (int j = 0; j < 8; ++j) {
                float o0 = acc2[j].x * inv + bb[2 * j];
                float o1 = acc2[j].y * inv + bb[2 * j + 1];
                pool[2 * j] += fmaxf(o0, 0.01f * o0);
                pool[2 * j + 1] += fmaxf(o1, 0.01f * o1);
            }
        }
    }
    if ((l & 31) < 8) {
#pragma unroll
        for (int k = 0; k < 16; ++k) atomicAdd(&spool[chb + k], pool[k]);
    }
    __syncthreads();
    if (tid < 128) {
        int slot = (blockIdx.x >> 3) & 63;
        float* dp = partAB + (gc ? 64 * 512 : 0) + (slot << 9) + head * 128 + tid;
        atomicAdd(dp, spool[tid]);
    }
}

// ---------------- fused mean-pool reduce + fc + concat ----------------
__global__ __launch_bounds__(256) void fc_final2(
    const float* __restrict__ partAB, const float* __restrict__ w, const float* __restrict__ b,
    float* __restrict__ out, float invN) {
    __shared__ float gA[512], gB[512];
    __shared__ float rA[256], rB[256];
    int t = threadIdx.x;
    for (int i = t; i < 512; i += 256) {
        float sA = 0.f, sB = 0.f;
        for (int r = 0; r < 64; ++r) {
            sA += partAB[r * 512 + i];
            sB += partAB[64 * 512 + r * 512 + i];
        }
        gA[i] = sA * invN;
        gB[i] = sB * invN;
    }
    __syncthreads();
    int jj = t & 31, ks = t >> 5;
    int j = blockIdx.x * 32 + jj;
    float sA = 0.f, sB = 0.f;
    for (int k = ks * 64; k < ks * 64 + 64; ++k) {
        float wv = w[k * 512 + j];
        sA += gA[k] * wv;
        sB += gB[k] * wv;
    }
    rA[t] = sA;
    rB[t] = sB;
    __syncthreads();
    if (ks == 0) {
#pragma unroll
        for (int s2 = 1; s2 < 8; ++s2) {
            sA += rA[jj + 32 * s2];
            sB += rB[jj + 32 * s2];
        }
        sA += b[j];
        sB += b[j];
        sA = sA >= 0.f ? sA : 0.01f * sA;
        sB = sB >= 0.f ? sB : 0.01f * sB;
        out[j] = sA;
        out[512 + j] = sB;
        out[1024 + j] = sA - sB;
    }
}

// ---------------- launch ----------------
extern "C" void kernel_launch(void* const* d_in, const int* in_sizes, int n_in,
                              void* d_out, int out_size, void* d_ws, size_t ws_size,
                              hipStream_t stream) {
    const float* x = (const float*)d_in[0];
    const int* adj = (const int*)d_in[1];
    const float* wtx = (const float*)d_in[2];
    const int* wadj = (const int*)d_in[3];
    const float* W = (const float*)d_in[4];
    const float* att_s = (const float*)d_in[5];
    const float* att_d = (const float*)d_in[6];
    const float* bias = (const float*)d_in[7];
    const float* fc1w = (const float*)d_in[8];
    const float* fc1b = (const float*)d_in[9];
    float* out = (float*)d_out;

    const int N = in_sizes[0] / 512;  // 20000
    const int E = in_sizes[1] / 2;    // 320000
    const int Mpad = ((N + 127) / 128) * 128;
    const int R2 = 2 * Mpad;          // hrow space

    char* p = (char*)d_ws;
    auto alloc = [&](size_t bytes) -> char* {
        char* r = p;
        p += (bytes + 255) & ~(size_t)255;
        return r;
    };
    unsigned char* h8 = (unsigned char*)alloc((size_t)R2 * 512);
    u16* Wt = (u16*)alloc(512 * 512 * 2);
    float* asrc = (float*)alloc((size_t)R2 * 4 * 4);
    float* adst = (float*)alloc((size_t)R2 * 4 * 4);
    int* deg = (int*)alloc((size_t)R2 * 4);
    int* off = (int*)alloc((size_t)(R2 + 1) * 4);
    int* cursor = (int*)alloc((size_t)R2 * 4);
    int* csrc = (int*)alloc((size_t)2 * (E + N) * 4);
    float* partAB = (float*)alloc((size_t)2 * 64 * 512 * 4);

    // cast_wt also zeroes deg + partAB (absorbs the 2 memset dispatches)
    cast_wt_kernel<<<64, 256, 0, stream>>>(W, Wt, deg, partAB, R2);

    // CSR build (independent of GEMM)
    csr_count<<<(2 * E + 255) / 256, 256, 0, stream>>>(adj, wadj, E, Mpad, deg);
    scan_fused<<<1, 1024, 0, stream>>>(deg, off, cursor, csrc, R2, N, Mpad);
    csr_scatter<<<(2 * E + 255) / 256, 256, 0, stream>>>(adj, wadj, E, Mpad, cursor, csrc);

    // fused GEMM: one block per 64-row tile, all heads (A staged once, dbuf + swizzled LDS)
    gemm_fused6<<<R2 / 64, 256, 0, stream>>>(x, wtx, Wt, h8, att_s, att_d, asrc, adst, N, Mpad);

    gat_aggregate13<<<1536, 256, 0, stream>>>(h8, asrc, adst, off, csrc, bias, partAB, Mpad);

    fc_final2<<<16, 256, 0, stream>>>(partAB, fc1w, fc1b, out, 1.0f / (float)N);
}

// Round 15
// 308.100 us; speedup vs baseline: 1.2406x; 1.1566x over previous
//
#include <hip/hip_runtime.h>
#include <hip/hip_bf16.h>

typedef unsigned short u16;
typedef short bf16x8 __attribute__((ext_vector_type(8)));
typedef float f32x4 __attribute__((ext_vector_type(4)));
typedef float f32x2 __attribute__((ext_vector_type(2)));

__device__ __forceinline__ u16 f2b(float f) {
    unsigned x = __float_as_uint(f);
    return (u16)((x + 0x7fffu + ((x >> 16) & 1u)) >> 16);
}

// pack two f32 to bf16x2 by truncation: one v_perm_b32
__device__ __forceinline__ int pkbf(float lo, float hi) {
    return __builtin_amdgcn_perm(__float_as_uint(hi), __float_as_uint(lo), 0x07060302);
}

// packed dual-f32 FMA: acc = f * ex + acc (VOP3P)
__device__ __forceinline__ void pkfma(f32x2& acc, f32x2 f, f32x2 ex) {
    asm("v_pk_fma_f32 %0, %1, %2, %0" : "+v"(acc) : "v"(f), "v"(ex));
}

// ---------------- fat kernel A: cast_wt (blocks 0..63) || csr_count (blocks 64..) ---------
// Independent work overlapped in one dispatch (single stream serializes separate launches).
__global__ __launch_bounds__(256) void castwt_count(
    const float* __restrict__ W, u16* __restrict__ Wt,
    const int* __restrict__ adj, const int* __restrict__ wadj,
    int E, int Mpad, int* __restrict__ deg) {
    __shared__ u16 tile[64][65];
    if (blockIdx.x < 64) {
        int tx = threadIdx.x & 63, ty = threadIdx.x >> 6;  // 64 x 4
        int bx = blockIdx.x & 7, by = blockIdx.x >> 3;
#pragma unroll
        for (int r = 0; r < 16; ++r) {
            int row = ty + (r << 2);
            tile[tx][row] = f2b(W[(by * 64 + row) * 512 + bx * 64 + tx]);
        }
        __syncthreads();
#pragma unroll
        for (int r = 0; r < 16; ++r) {
            int row = ty + (r << 2);
            Wt[(bx * 64 + row) * 512 + by * 64 + tx] = tile[row][tx];
        }
    } else {
        int i = (blockIdx.x - 64) * 256 + threadIdx.x;
        if (i < 2 * E) {
            int d = (i < E) ? adj[E + i] : (wadj[E + (i - E)] + Mpad);
            atomicAdd(&deg[d], 1);
        }
    }
}

// ---------------- fat kernel B: gemm_fused6 (blocks 0..gemmB-1) || csr_scatter ------------
// gemm runs 628 blocks at 2/CU (512 slots): round 2 has only 116 blocks -> ~77% idle tail.
// Appending scatter's 2500 tiny blocks backfills that tail (saves scatter's ~20 us serial).
__global__ __launch_bounds__(256, 2) void gemm_scatter(
    const float* __restrict__ xA, const float* __restrict__ xW, const u16* __restrict__ Bt,
    unsigned char* __restrict__ h8, const float* __restrict__ att_src,
    const float* __restrict__ att_dst, float* __restrict__ asrc, float* __restrict__ adst,
    int N, int Mpad, int gemmB,
    const int* __restrict__ adj, const int* __restrict__ wadj, int E,
    int* __restrict__ cursor, int* __restrict__ csrc) {
    __shared__ float lA[2][64 * 32];   // 16 KB
    __shared__ u16 lB[2][512 * 32];    // 64 KB
    if (blockIdx.x >= gemmB) {
        // ---- csr_scatter ----
        int i = (blockIdx.x - gemmB) * 256 + threadIdx.x;
        if (i < 2 * E) {
            int s, d;
            if (i < E) {
                s = adj[i];
                d = adj[E + i];
            } else {
                s = wadj[i - E] + Mpad;
                d = wadj[E + (i - E)] + Mpad;
            }
            int p = atomicAdd(&cursor[d], 1);
            csrc[p] = s;
        }
        return;
    }
    // ---- gemm_fused6 body ----
    const int tid = threadIdx.x;
    const int w = tid >> 6, l = tid & 63;   // wave w = head w
    const int row0 = blockIdx.x * 64;
    const int head = w;
    const int mlane = l & 15, quad = l >> 4;
    const int R2v = 2 * Mpad;

    const float* src = (row0 >= Mpad) ? xW : xA;
    const int rbase = row0 - (row0 >= Mpad ? Mpad : 0);
    const int arow = (l >> 3);                             // A row (mod 8) at stage time
    const int acol = (((l & 7) ^ arow) << 2);              // pre-swizzled source chunk (floats)
    const int brow = (l >> 2);                             // B row (mod 16) at stage time
    const int bcol = (((l & 3) ^ ((l >> 3) & 3)) << 3);    // pre-swizzled source chunk (u16)

    auto stage = [&](int b, int k0) {
#pragma unroll
        for (int g = 0; g < 2; ++g) {
            int lrow = rbase + (w << 4) + (g << 3) + arow;
            lrow = min(lrow, N - 1);  // pad rows: clamp (results are don't-care)
            const float* ga = src + (size_t)lrow * 512 + k0 + acol;
            float* la = &lA[b][((w << 4) + (g << 3)) << 5];  // wave-uniform base, linear dest
            __builtin_amdgcn_global_load_lds((const __attribute__((address_space(1))) void*)ga,
                                             (__attribute__((address_space(3))) void*)la, 16, 0, 0);
        }
#pragma unroll
        for (int s = 0; s < 8; ++s) {
            const u16* gb = Bt + (size_t)((w << 7) + (s << 4) + brow) * 512 + (k0 + bcol);
            u16* lb = &lB[b][((w << 7) + (s << 4)) << 5];  // wave-uniform base, linear dest
            __builtin_amdgcn_global_load_lds((const __attribute__((address_space(1))) void*)gb,
                                             (__attribute__((address_space(3))) void*)lb, 16, 0, 0);
        }
    };

    f32x4 acc[4][8];
#pragma unroll
    for (int i = 0; i < 4; i++)
#pragma unroll
        for (int j = 0; j < 8; j++) acc[i][j] = f32x4{0.f, 0.f, 0.f, 0.f};

    stage(0, 0);
    __syncthreads();
    int cur = 0;
    for (int t = 0; t < 16; ++t) {
        if (t < 15) stage(cur ^ 1, (t + 1) << 5);  // next-tile loads in flight under compute
        bf16x8 af[4], bfr[8];
#pragma unroll
        for (int i = 0; i < 4; i++) {
            const float* rb = &lA[cur][(i * 16 + mlane) * 32];
            float4 f0 = *(const float4*)(rb + (((quad * 2) ^ (mlane & 7)) << 2));
            float4 f1 = *(const float4*)(rb + (((quad * 2 + 1) ^ (mlane & 7)) << 2));
            int* ai = (int*)&af[i];
            ai[0] = pkbf(f0.x, f0.y);
            ai[1] = pkbf(f0.z, f0.w);
            ai[2] = pkbf(f1.x, f1.y);
            ai[3] = pkbf(f1.z, f1.w);
        }
#pragma unroll
        for (int j = 0; j < 8; j++)
            bfr[j] = *(const bf16x8*)&lB[cur][((w << 7) + j * 16 + mlane) * 32 +
                                             ((quad ^ ((mlane >> 1) & 3)) << 3)];
#pragma unroll
        for (int i = 0; i < 4; i++)
#pragma unroll
            for (int j = 0; j < 8; j++)
                acc[i][j] = __builtin_amdgcn_mfma_f32_16x16x32_bf16(af[i], bfr[j], acc[i][j], 0, 0, 0);
        __syncthreads();  // drains next-tile loads; also protects buffer reuse
        cur ^= 1;
    }

    float as_j[8], ad_j[8];
#pragma unroll
    for (int j = 0; j < 8; j++) {
        as_j[j] = att_src[(head << 7) + j * 16 + mlane];
        ad_j[j] = att_dst[(head << 7) + j * 16 + mlane];
    }
#pragma unroll
    for (int i = 0; i < 4; i++) {
#pragma unroll
        for (int r = 0; r < 4; r++) {
            float vs = 0.f, vd = 0.f;
#pragma unroll
            for (int j = 0; j < 8; j++) {
                float hv = acc[i][j][r];
                vs += hv * as_j[j];
                vd += hv * ad_j[j];
            }
#pragma unroll
            for (int o = 8; o >= 1; o >>= 1) {
                vs += __shfl_xor(vs, o);
                vd += __shfl_xor(vd, o);
            }
            if (mlane == 0) {
                int rg = row0 + i * 16 + quad * 4 + r;
                asrc[head * R2v + rg] = vs;
                adst[head * R2v + rg] = vd;
            }
        }
    }

    // h8 epilogue: fp8-pack into LDS tile (64 rows x 512 bytes, XOR-swizzled), then
    // coalesced dwordx4 stores. lB[0] is free after the final k-loop barrier.
    unsigned char* hstage = (unsigned char*)&lB[0][0];  // 32 KB
#pragma unroll
    for (int i = 0; i < 4; i++)
#pragma unroll
        for (int j = 0; j < 8; j++)
#pragma unroll
            for (int r = 0; r < 4; r++) {
                int row = i * 16 + quad * 4 + r;
                int colb = (w << 7) + j * 16 + mlane;  // [head*128 + cc]
                float v = acc[i][j][r];
                unsigned pk = __builtin_amdgcn_cvt_pk_fp8_f32(v, v, 0, false);
                hstage[row * 512 + (colb ^ ((row & 7) << 4))] = (unsigned char)(pk & 0xff);
            }
    __syncthreads();
#pragma unroll
    for (int k = 0; k < 8; ++k) {
        int c = (k << 8) + tid;   // chunk index [0,2048): 2048 x 16B = 32 KB
        int hd = c >> 9;          // 512 chunks per head
        int rem = c & 511;
        int row = rem >> 3;       // 8 chunks per 128-byte head-row
        int cch = rem & 7;
        int lofs = row * 512 + ((((hd << 7) + (cch << 4))) ^ ((row & 7) << 4));
        int4 v = *(const int4*)&hstage[lofs];
        *(int4*)&h8[(((size_t)(hd * R2v + row0 + row)) << 7) + (cch << 4)] = v;
    }
}

// ---------------- CSR scans (r12 proven config: parallel 3-kernel pipeline) ---------------
__global__ __launch_bounds__(256) void scanA(const int* __restrict__ deg, int* __restrict__ off,
                                             int* __restrict__ bsum, int n, int N, int Mpad) {
    __shared__ int wsum[4];
    int tid = threadIdx.x, lane = tid & 63, wid = tid >> 6;
    int i = blockIdx.x * 256 + tid;
    int valid = (i < N) || (i >= Mpad && i < Mpad + N);
    int d = (i < n) ? deg[i] + (valid ? 1 : 0) : 0;
    int x = d;
#pragma unroll
    for (int o = 1; o < 64; o <<= 1) {
        int y = __shfl_up(x, (unsigned)o, 64);
        if (lane >= o) x += y;
    }
    if (lane == 63) wsum[wid] = x;
    __syncthreads();
    int woff = 0;
    for (int j = 0; j < wid; ++j) woff += wsum[j];
    if (i < n) off[i] = woff + x - d;
    if (tid == 255) bsum[blockIdx.x] = woff + x;
}

__global__ __launch_bounds__(256) void scanB(const int* __restrict__ bsum, int* __restrict__ bbase,
                                             int nb, int* __restrict__ off, int n) {
    __shared__ int wsum[4];
    int tid = threadIdx.x, lane = tid & 63, wid = tid >> 6;
    int d = (tid < nb) ? bsum[tid] : 0;
    int x = d;
#pragma unroll
    for (int o = 1; o < 64; o <<= 1) {
        int y = __shfl_up(x, (unsigned)o, 64);
        if (lane >= o) x += y;
    }
    if (lane == 63) wsum[wid] = x;
    __syncthreads();
    int woff = 0;
    for (int j = 0; j < wid; ++j) woff += wsum[j];
    int excl = woff + x - d;
    if (tid < nb) bbase[tid] = excl;
    if (tid == nb - 1) off[n] = excl + d;
}

__global__ void scanC(int* __restrict__ off, const int* __restrict__ bbase,
                      int* __restrict__ cursor, int* __restrict__ csrc, int n, int N, int Mpad) {
    int i = blockIdx.x * blockDim.x + threadIdx.x;
    if (i < n) {
        int o = off[i] + bbase[i >> 8];
        off[i] = o;
        int valid = (i < N) || (i >= Mpad && i < Mpad + N);
        if (valid) csrc[o] = i;  // self loop (hrow)
        cursor[i] = o + valid;
    }
}

// ---------------- fused softmax + gather v13: (head,graph)-per-XCD, 3-deep pipeline --------
// Proven 78.6us config. launch_bounds(256,6) = 85-reg cap >= ~80-reg live set. Never cap
// below 85 (r10/r13 spills). 1536 blocks = 256 CU x 6 co-resident, single round.
__global__ __launch_bounds__(256, 6) void gat_aggregate13(
    const unsigned char* __restrict__ h8, const float* __restrict__ asrc,
    const float* __restrict__ adst, const int* __restrict__ off, const int* __restrict__ csrc,
    const float* __restrict__ bias, float* __restrict__ partAB, int Mpad) {
    const int R2 = 2 * Mpad;
    __shared__ float spool[128];  // this block's (head, graph) 128 channels
    int tid = threadIdx.x;
    if (tid < 128) spool[tid] = 0.f;
    __syncthreads();
    const int wv = tid >> 6, l = tid & 63;
    const int gi = (l >> 3) & 3;  // edge slot within half (0..3)
    const int hi = l >> 5;        // which dst of the pair (0/1)
    const int chb = (l & 7) << 4; // channel byte offset within 128 (16 B per lane)
    const int head = (blockIdx.x & 7) >> 1;
    const int gc = blockIdx.x & 1;  // graph 0=A, 1=B
    const unsigned char* h8h = h8 + (((size_t)head * R2) << 7);
    const float* ash = asrc + (size_t)head * R2;
    const float* adh = adst + (size_t)head * R2;
    float bb[16];
#pragma unroll
    for (int k = 0; k < 16; ++k) bb[k] = bias[head * 128 + chb + k];
    float pool[16];
#pragma unroll
    for (int k = 0; k < 16; ++k) pool[k] = 0.f;

    const int hb = gc * Mpad;
    const int half = Mpad >> 1;  // Mpad even; N even -> pairs never split valid/pad
    int widx = ((blockIdx.x >> 3) << 2) + wv;
    const int cstride = gridDim.x >> 1;  // (gridDim/8)*4

    for (int p = widx; p < half; p += cstride) {
        int d0 = (p << 1) + hb;
        int q0 = off[d0], q1 = off[d0 + 1], q2 = off[d0 + 2];
        int n0 = q1 - q0, n1 = q2 - q1;
        int nmax = max(n0, n1);
        if (nmax == 0) continue;  // pad pair
        int nm = hi ? n1 : n0;
        int qm = hi ? q1 : q0;
        float ad = adh[d0 + hi];
        f32x2 acc2[8];
#pragma unroll
        for (int j = 0; j < 8; ++j) acc2[j] = f32x2{0.f, 0.f};
        float dsum = 0.f;

        int i0 = gi, i1 = 4 + gi, i2 = 8 + gi, i3 = 12 + gi;
        int E0 = csrc[qm + ((i0 < nm) ? i0 : 0)];
        int E1 = csrc[qm + ((i1 < nm) ? i1 : 0)];
        int E2 = csrc[qm + ((i2 < nm) ? i2 : 0)];
        int E3 = csrc[qm + ((i3 < nm) ? i3 : 0)];
        float A0 = ash[E0];
        int4 H0 = *(const int4*)(h8h + (((size_t)E0) << 7) + chb);
        float A1 = ash[E1];
        int4 H1 = *(const int4*)(h8h + (((size_t)E1) << 7) + chb);

#pragma unroll 2
        for (int base = 0; base < nmax; base += 4) {
            int i4 = base + 16 + gi;
            int E4 = csrc[qm + ((i4 < nm) ? i4 : 0)];
            float A2 = ash[E2];
            int4 H2 = *(const int4*)(h8h + (((size_t)E2) << 7) + chb);
            float e = A0 + ad;
            float em = fmaxf(e, 0.2f * e);
            float ex = __expf(em);
            ex = ((base + gi) < nm) ? ex : 0.f;
            dsum += ex;
            f32x2 exv = {ex, ex};
            f32x2 f;
            f = __builtin_amdgcn_cvt_pk_f32_fp8(H0.x, false); pkfma(acc2[0], f, exv);
            f = __builtin_amdgcn_cvt_pk_f32_fp8(H0.x, true);  pkfma(acc2[1], f, exv);
            f = __builtin_amdgcn_cvt_pk_f32_fp8(H0.y, false); pkfma(acc2[2], f, exv);
            f = __builtin_amdgcn_cvt_pk_f32_fp8(H0.y, true);  pkfma(acc2[3], f, exv);
            f = __builtin_amdgcn_cvt_pk_f32_fp8(H0.z, false); pkfma(acc2[4], f, exv);
            f = __builtin_amdgcn_cvt_pk_f32_fp8(H0.z, true);  pkfma(acc2[5], f, exv);
            f = __builtin_amdgcn_cvt_pk_f32_fp8(H0.w, false); pkfma(acc2[6], f, exv);
            f = __builtin_amdgcn_cvt_pk_f32_fp8(H0.w, true);  pkfma(acc2[7], f, exv);
            A0 = A1; H0 = H1;
            A1 = A2; H1 = H2;
            E2 = E3; E3 = E4;
        }
        dsum += __shfl_xor(dsum, 8);
        dsum += __shfl_xor(dsum, 16);
#pragma unroll
        for (int j = 0; j < 8; ++j) {
            acc2[j].x += __shfl_xor(acc2[j].x, 8);
            acc2[j].y += __shfl_xor(acc2[j].y, 8);
            acc2[j].x += __shfl_xor(acc2[j].x, 16);
            acc2[j].y += __shfl_xor(acc2[j].y, 16);
        }
        if (nm > 0) {
            float inv = 1.f / (dsum + 1e-16f);
#pragma unroll
            for (int j = 0; j < 8; ++j) {
                float o0 = acc2[j].x * inv + bb[2 * j];
                float o1 = acc2[j].y * inv + bb[2 * j + 1];
                pool[2 * j] += fmaxf(o0, 0.01f * o0);
                pool[2 * j + 1] += fmaxf(o1, 0.01f * o1);
            }
        }
    }
    if ((l & 31) < 8) {
#pragma unroll
        for (int k = 0; k < 16; ++k) atomicAdd(&spool[chb + k], pool[k]);
    }
    __syncthreads();
    if (tid < 128) {
        int slot = (blockIdx.x >> 3) & 63;
        float* dp = partAB + (gc ? 64 * 512 : 0) + (slot << 9) + head * 128 + tid;
        atomicAdd(dp, spool[tid]);
    }
}

// ---------------- fused mean-pool reduce + fc + concat ----------------
__global__ __launch_bounds__(256) void fc_final2(
    const float* __restrict__ partAB, const float* __restrict__ w, const float* __restrict__ b,
    float* __restrict__ out, float invN) {
    __shared__ float gA[512], gB[512];
    __shared__ float rA[256], rB[256];
    int t = threadIdx.x;
    for (int i = t; i < 512; i += 256) {
        float sA = 0.f, sB = 0.f;
        for (int r = 0; r < 64; ++r) {
            sA += partAB[r * 512 + i];
            sB += partAB[64 * 512 + r * 512 + i];
        }
        gA[i] = sA * invN;
        gB[i] = sB * invN;
    }
    __syncthreads();
    int jj = t & 31, ks = t >> 5;
    int j = blockIdx.x * 32 + jj;
    float sA = 0.f, sB = 0.f;
    for (int k = ks * 64; k < ks * 64 + 64; ++k) {
        float wv = w[k * 512 + j];
        sA += gA[k] * wv;
        sB += gB[k] * wv;
    }
    rA[t] = sA;
    rB[t] = sB;
    __syncthreads();
    if (ks == 0) {
#pragma unroll
        for (int s2 = 1; s2 < 8; ++s2) {
            sA += rA[jj + 32 * s2];
            sB += rB[jj + 32 * s2];
        }
        sA += b[j];
        sB += b[j];
        sA = sA >= 0.f ? sA : 0.01f * sA;
        sB = sB >= 0.f ? sB : 0.01f * sB;
        out[j] = sA;
        out[512 + j] = sB;
        out[1024 + j] = sA - sB;
    }
}

// ---------------- launch ----------------
extern "C" void kernel_launch(void* const* d_in, const int* in_sizes, int n_in,
                              void* d_out, int out_size, void* d_ws, size_t ws_size,
                              hipStream_t stream) {
    const float* x = (const float*)d_in[0];
    const int* adj = (const int*)d_in[1];
    const float* wtx = (const float*)d_in[2];
    const int* wadj = (const int*)d_in[3];
    const float* W = (const float*)d_in[4];
    const float* att_s = (const float*)d_in[5];
    const float* att_d = (const float*)d_in[6];
    const float* bias = (const float*)d_in[7];
    const float* fc1w = (const float*)d_in[8];
    const float* fc1b = (const float*)d_in[9];
    float* out = (float*)d_out;

    const int N = in_sizes[0] / 512;  // 20000
    const int E = in_sizes[1] / 2;    // 320000
    const int Mpad = ((N + 127) / 128) * 128;
    const int R2 = 2 * Mpad;          // hrow space
    const int nb = (R2 + 255) / 256;  // 157
    const int eb = (2 * E + 255) / 256;  // 2500

    char* p = (char*)d_ws;
    auto alloc = [&](size_t bytes) -> char* {
        char* r = p;
        p += (bytes + 255) & ~(size_t)255;
        return r;
    };
    unsigned char* h8 = (unsigned char*)alloc((size_t)R2 * 512);
    u16* Wt = (u16*)alloc(512 * 512 * 2);
    float* asrc = (float*)alloc((size_t)R2 * 4 * 4);
    float* adst = (float*)alloc((size_t)R2 * 4 * 4);
    int* deg = (int*)alloc((size_t)R2 * 4);
    int* off = (int*)alloc((size_t)(R2 + 1) * 4);
    int* cursor = (int*)alloc((size_t)R2 * 4);
    int* bsum = (int*)alloc(256 * 4);
    int* bbase = (int*)alloc(256 * 4);
    int* csrc = (int*)alloc((size_t)2 * (E + N) * 4);
    float* partAB = (float*)alloc((size_t)2 * 64 * 512 * 4);

    hipMemsetAsync(partAB, 0, (size_t)2 * 64 * 512 * 4, stream);
    hipMemsetAsync(deg, 0, (size_t)R2 * 4, stream);

    // fat A: W^T cast (64 blocks) || edge degree count (2500 blocks)
    castwt_count<<<64 + eb, 256, 0, stream>>>(W, Wt, adj, wadj, E, Mpad, deg);

    scanA<<<nb, 256, 0, stream>>>(deg, off, bsum, R2, N, Mpad);
    scanB<<<1, 256, 0, stream>>>(bsum, bbase, nb, off, R2);
    scanC<<<nb, 256, 0, stream>>>(off, bbase, cursor, csrc, R2, N, Mpad);

    // fat B: fused GEMM (628 blocks) || csr_scatter (2500 blocks) — scatter backfills the
    // gemm tail (round 2 has only 116/512 slots busy).
    gemm_scatter<<<R2 / 64 + eb, 256, 0, stream>>>(x, wtx, Wt, h8, att_s, att_d, asrc, adst,
                                                   N, Mpad, R2 / 64, adj, wadj, E, cursor, csrc);

    gat_aggregate13<<<1536, 256, 0, stream>>>(h8, asrc, adst, off, csrc, bias, partAB, Mpad);

    fc_final2<<<16, 256, 0, stream>>>(partAB, fc1w, fc1b, out, 1.0f / (float)N);
}